// Round 9
// baseline (76.963 us; speedup 1.0000x reference)
//
#include <hip/hip_runtime.h>
#include <math.h>

// Problem constants (x: (16, 1, 3, 1024, 1024) fp32)
#define W      1024            // columns
#define H      1024            // rows per batch image
#define FRAME  (1024 * 1024)   // elements per frame
#define BSTR   (3 * FRAME)     // elements per batch (3 frames)
#define ROWS   16384           // flattened rows
#define NCHUNK 512             // row chunks in pass 1 (32 contiguous rows each)

typedef float v4f __attribute__((ext_vector_type(4)));
typedef unsigned v4u __attribute__((ext_vector_type(4)));

// order-preserving float <-> uint (exact atomic min/max; validated round 1)
__device__ __forceinline__ unsigned f2o(float f) {
    unsigned b = __float_as_uint(f);
    return b ^ (unsigned)(((int)b >> 31) | (int)0x80000000);
}
__device__ __forceinline__ float o2f(unsigned u) {
    unsigned mask = (u & 0x80000000u) ? 0x80000000u : 0xFFFFFFFFu;
    return __uint_as_float(u ^ mask);
}

__device__ __forceinline__ v4f min4(v4f a, v4f b) {
    v4f r; r.x = fminf(a.x,b.x); r.y = fminf(a.y,b.y); r.z = fminf(a.z,b.z); r.w = fminf(a.w,b.w); return r;
}
__device__ __forceinline__ v4f max4(v4f a, v4f b) {
    v4f r; r.x = fmaxf(a.x,b.x); r.y = fmaxf(a.y,b.y); r.z = fmaxf(a.z,b.z); r.w = fmaxf(a.w,b.w); return r;
}

// ---- reset: atomic identities (every launch; ws state never matters) ----
__global__ __launch_bounds__(1024) void reset_k(unsigned* __restrict__ tbl) {
    tbl[blockIdx.x * 1024 + threadIdx.x] =
        (blockIdx.x == 0) ? 0xFFFFFFFFu : 0u;   // mn: +inf enc, mx: -inf enc
}

// ---- Pass 1: per-column min/max. EXACT round-6 shape: 2048 blocks =
// 4 col-groups x 512 row-chunks (32 contiguous rows each), 8 blocks/CU.
// Tail: 8 atomics per surviving lane instead of partial stores. ----
__global__ __launch_bounds__(256) void minmax_k(const float* __restrict__ x,
                                                unsigned* __restrict__ mn_u,
                                                unsigned* __restrict__ mx_u) {
    const int cgp  = blockIdx.x & 3;    // column group, 256 cols each
    const int ch   = blockIdx.x >> 2;   // row chunk (0..511), 32 rows each
    const int lane = threadIdx.x & 63;
    const int wid  = threadIdx.x >> 6;  // wave in block (0..3)
    const int col  = cgp * 256 + lane * 4;

    const float INF = __builtin_inff();
    v4f vmin; vmin.x = vmin.y = vmin.z = vmin.w = INF;
    v4f vmax; vmax.x = vmax.y = vmax.z = vmax.w = -INF;

    const int r0 = ch * (ROWS / NCHUNK);   // 32 rows per chunk
    const int b  = r0 >> 10;
    const int hh = r0 & (H - 1);
    const float* p0 = x + (size_t)b * BSTR + ((size_t)hh << 10) + col;

    if (r0 < H) {
        // batch 0: second difference frame2 - frame0 (uniform per block)
#pragma unroll
        for (int i = 0; i < 8; ++i) {
            int off = ((i << 2) + wid) << 10;
            v4f f0 = *(const v4f*)(p0 + off);
            v4f f2 = *(const v4f*)(p0 + off + 2 * FRAME);
            v4f v  = f2 - f0;
            vmin = min4(vmin, v);
            vmax = max4(vmax, v);
        }
    } else {
        // batches 1..15: frame 0 passthrough
#pragma unroll
        for (int i = 0; i < 8; ++i) {
            int off = ((i << 2) + wid) << 10;
            v4f v = *(const v4f*)(p0 + off);
            vmin = min4(vmin, v);
            vmax = max4(vmax, v);
        }
    }

    __shared__ v4f smin[4][64];
    __shared__ v4f smax[4][64];
    smin[wid][lane] = vmin;
    smax[wid][lane] = vmax;
    __syncthreads();

    if (threadIdx.x < 64) {
        v4f m = min4(min4(smin[0][lane], smin[1][lane]),
                     min4(smin[2][lane], smin[3][lane]));
        v4f M = max4(max4(smax[0][lane], smax[1][lane]),
                     max4(smax[2][lane], smax[3][lane]));
        atomicMin(&mn_u[col + 0], f2o(m.x));
        atomicMin(&mn_u[col + 1], f2o(m.y));
        atomicMin(&mn_u[col + 2], f2o(m.z));
        atomicMin(&mn_u[col + 3], f2o(m.w));
        atomicMax(&mx_u[col + 0], f2o(M.x));
        atomicMax(&mx_u[col + 1], f2o(M.y));
        atomicMax(&mx_u[col + 2], f2o(M.z));
        atomicMax(&mx_u[col + 3], f2o(M.w));
    }
}

// ---- Pass 2: scaled output. EXACT round-6 shape: 8192 blocks x 256 thr x
// 2 vec4. Table decode + 1/den multiply per thread (8 KB table, L2-hot). ----
__global__ __launch_bounds__(256) void scale_k(const float* __restrict__ x,
                                               const unsigned* __restrict__ mn_u,
                                               const unsigned* __restrict__ mx_u,
                                               float* __restrict__ out) {
#pragma unroll
    for (int k = 0; k < 2; ++k) {
        int i4  = blockIdx.x * 512 + k * 256 + threadIdx.x;
        int idx = i4 << 2;
        int r   = idx >> 10;
        int col = idx & (W - 1);
        int b   = r >> 10;
        int hh  = r & (H - 1);
        const float* p = x + (size_t)b * BSTR + ((size_t)hh << 10) + col;
        v4f v = *(const v4f*)p;
        if (r < H) {
            v4f f2 = *(const v4f*)(p + 2 * FRAME);
            v = f2 - v;
        }
        v4u mu = *(const v4u*)(mn_u + col);
        v4u xu = *(const v4u*)(mx_u + col);
        v4f mn4, iv4;
        {
            float mn = o2f(mu.x), rng = o2f(xu.x) - mn;
            mn4.x = mn; iv4.x = 1.0f / ((rng == 0.0f) ? 1.0f : rng);
        }
        {
            float mn = o2f(mu.y), rng = o2f(xu.y) - mn;
            mn4.y = mn; iv4.y = 1.0f / ((rng == 0.0f) ? 1.0f : rng);
        }
        {
            float mn = o2f(mu.z), rng = o2f(xu.z) - mn;
            mn4.z = mn; iv4.z = 1.0f / ((rng == 0.0f) ? 1.0f : rng);
        }
        {
            float mn = o2f(mu.w), rng = o2f(xu.w) - mn;
            mn4.w = mn; iv4.w = 1.0f / ((rng == 0.0f) ? 1.0f : rng);
        }
        v4f o = (v - mn4) * iv4;
        *(v4f*)(out + idx) = o;
    }
}

extern "C" void kernel_launch(void* const* d_in, const int* in_sizes, int n_in,
                              void* d_out, int out_size, void* d_ws, size_t ws_size,
                              hipStream_t stream) {
    const float* x = (const float*)d_in[0];
    float* out = (float*)d_out;

    // ws layout: mn_u[1024] | mx_u[1024]  (8 KB)
    unsigned* mn_u = (unsigned*)d_ws;
    unsigned* mx_u = mn_u + W;

    reset_k<<<2, 1024, 0, stream>>>(mn_u);   // block 0 -> mn_u, block 1 -> mx_u
    minmax_k<<<2048, 256, 0, stream>>>(x, mn_u, mx_u);
    scale_k<<<8192, 256, 0, stream>>>(x, mn_u, mx_u, out);
}

// Round 10
// 41.426 us; speedup vs baseline: 1.8579x; 1.8579x over previous
//
#include <hip/hip_runtime.h>
#include <math.h>

// Problem constants (x: (16, 1, 3, 1024, 1024) fp32)
#define W      1024            // columns
#define H      1024            // rows per batch image
#define FRAME  (1024 * 1024)   // elements per frame
#define BSTR   (3 * FRAME)     // elements per batch (3 frames)
#define ROWS   16384           // flattened rows
#define NCHUNK 512             // row chunks in pass 1 (32 contiguous rows each)

typedef float v4f __attribute__((ext_vector_type(4)));

__device__ __forceinline__ v4f min4(v4f a, v4f b) {
    v4f r; r.x = fminf(a.x,b.x); r.y = fminf(a.y,b.y); r.z = fminf(a.z,b.z); r.w = fminf(a.w,b.w); return r;
}
__device__ __forceinline__ v4f max4(v4f a, v4f b) {
    v4f r; r.x = fmaxf(a.x,b.x); r.y = fmaxf(a.y,b.y); r.z = fmaxf(a.z,b.z); r.w = fmaxf(a.w,b.w); return r;
}

// ---- Pass 1: per-column partial min/max. EXACT round-6 kernel: 2048 blocks
// = 4 col-groups x 512 row-chunks (32 contiguous rows), 8 blocks/CU. ----
__global__ __launch_bounds__(256) void minmax_k(const float* __restrict__ x,
                                                float* __restrict__ pmin,
                                                float* __restrict__ pmax) {
    const int cgp  = blockIdx.x & 3;    // column group, 256 cols each
    const int ch   = blockIdx.x >> 2;   // row chunk (0..511), 32 rows each
    const int lane = threadIdx.x & 63;
    const int wid  = threadIdx.x >> 6;  // wave in block (0..3)
    const int col  = cgp * 256 + lane * 4;

    const float INF = __builtin_inff();
    v4f vmin; vmin.x = vmin.y = vmin.z = vmin.w = INF;
    v4f vmax; vmax.x = vmax.y = vmax.z = vmax.w = -INF;

    const int r0 = ch * (ROWS / NCHUNK);   // 32 rows per chunk
    const int b  = r0 >> 10;
    const int hh = r0 & (H - 1);
    const float* p0 = x + (size_t)b * BSTR + ((size_t)hh << 10) + col;

    if (r0 < H) {
        // batch 0: second difference frame2 - frame0 (uniform per block)
#pragma unroll
        for (int i = 0; i < 8; ++i) {
            int off = ((i << 2) + wid) << 10;
            v4f f0 = *(const v4f*)(p0 + off);
            v4f f2 = *(const v4f*)(p0 + off + 2 * FRAME);
            v4f v  = f2 - f0;
            vmin = min4(vmin, v);
            vmax = max4(vmax, v);
        }
    } else {
        // batches 1..15: frame 0 passthrough
#pragma unroll
        for (int i = 0; i < 8; ++i) {
            int off = ((i << 2) + wid) << 10;
            v4f v = *(const v4f*)(p0 + off);
            vmin = min4(vmin, v);
            vmax = max4(vmax, v);
        }
    }

    __shared__ v4f smin[4][64];
    __shared__ v4f smax[4][64];
    smin[wid][lane] = vmin;
    smax[wid][lane] = vmax;
    __syncthreads();

    if (threadIdx.x < 64) {
        v4f m = min4(min4(smin[0][lane], smin[1][lane]),
                     min4(smin[2][lane], smin[3][lane]));
        v4f M = max4(max4(smax[0][lane], smax[1][lane]),
                     max4(smax[2][lane], smax[3][lane]));
        *(v4f*)(pmin + ch * W + col) = m;
        *(v4f*)(pmax + ch * W + col) = M;
    }
}

// ---- Pass 2: reduce 512 partials/column. 128 blocks (4x parallelism vs r6):
// 8 cols x 32 subs per block, each thread reduces 16 chunks. ----
__global__ __launch_bounds__(256) void finalize_k(const float* __restrict__ pmin,
                                                  const float* __restrict__ pmax,
                                                  float* __restrict__ mn_f,
                                                  float* __restrict__ inv_f) {
    const int c   = threadIdx.x & 7;          // col within block (0..7)
    const int sub = threadIdx.x >> 3;         // 0..31 chunk slice
    const int col = blockIdx.x * 8 + c;

    float mn = __builtin_inff();
    float mx = -__builtin_inff();
#pragma unroll
    for (int k = 0; k < NCHUNK / 32; ++k) {
        int ch = sub * (NCHUNK / 32) + k;
        mn = fminf(mn, pmin[ch * W + col]);
        mx = fmaxf(mx, pmax[ch * W + col]);
    }

    __shared__ float smn[32][8];
    __shared__ float smx[32][8];
    smn[sub][c] = mn;
    smx[sub][c] = mx;
    __syncthreads();

    if (threadIdx.x < 8) {
        float m = smn[0][c], M = smx[0][c];
#pragma unroll
        for (int s = 1; s < 32; ++s) {
            m = fminf(m, smn[s][c]);
            M = fmaxf(M, smx[s][c]);
        }
        float rng = M - m;
        float den = (rng == 0.0f) ? 1.0f : rng;  // _handle_zeros_in_scale
        mn_f[col]  = m;
        inv_f[col] = 1.0f / den;
    }
}

// ---- Pass 3: scaled output. 8192 blocks x 2 rows each. col = 4*tid is
// loop-invariant -> table loaded once; batch/branch block-uniform. ----
__global__ __launch_bounds__(256) void scale_k(const float* __restrict__ x,
                                               const float* __restrict__ mn_f,
                                               const float* __restrict__ inv_f,
                                               float* __restrict__ out) {
    const int col = threadIdx.x << 2;     // invariant across both rows
    const int r0  = blockIdx.x * 2;       // rows r0, r0+1 (same batch always)
    const int b   = r0 >> 10;
    const int hh  = r0 & (H - 1);

    const float* p = x + (size_t)b * BSTR + ((size_t)hh << 10) + col;
    float* q = out + ((size_t)r0 << 10) + col;

    const v4f mn4 = *(const v4f*)(mn_f + col);
    const v4f iv4 = *(const v4f*)(inv_f + col);

    if (r0 < H) {
        // batch 0: second difference frame2 - frame0 (uniform per block)
#pragma unroll
        for (int k = 0; k < 2; ++k) {
            v4f f0 = *(const v4f*)(p + (k << 10));
            v4f f2 = *(const v4f*)(p + (k << 10) + 2 * FRAME);
            *(v4f*)(q + (k << 10)) = ((f2 - f0) - mn4) * iv4;
        }
    } else {
#pragma unroll
        for (int k = 0; k < 2; ++k) {
            v4f v = *(const v4f*)(p + (k << 10));
            *(v4f*)(q + (k << 10)) = (v - mn4) * iv4;
        }
    }
}

extern "C" void kernel_launch(void* const* d_in, const int* in_sizes, int n_in,
                              void* d_out, int out_size, void* d_ws, size_t ws_size,
                              hipStream_t stream) {
    const float* x = (const float*)d_in[0];
    float* out = (float*)d_out;

    // ws layout: pmin[512*1024] | pmax[512*1024] | mn_f[1024] | inv_f[1024]
    float* pmin = (float*)d_ws;
    float* pmax = pmin + NCHUNK * W;
    float* mn_f = pmax + NCHUNK * W;
    float* inv_f = mn_f + W;

    minmax_k<<<2048, 256, 0, stream>>>(x, pmin, pmax);
    finalize_k<<<128, 256, 0, stream>>>(pmin, pmax, mn_f, inv_f);
    scale_k<<<8192, 256, 0, stream>>>(x, mn_f, inv_f, out);
}

// Round 11
// 40.652 us; speedup vs baseline: 1.8932x; 1.0190x over previous
//
#include <hip/hip_runtime.h>
#include <math.h>

// Problem constants (x: (16, 1, 3, 1024, 1024) fp32)
#define W      1024            // columns
#define H      1024            // rows per batch image
#define FRAME  (1024 * 1024)   // elements per frame
#define BSTR   (3 * FRAME)     // elements per batch (3 frames)
#define ROWS   16384           // flattened rows
#define NCHUNK 512             // row chunks in pass 1 (32 contiguous rows each)

typedef float v4f __attribute__((ext_vector_type(4)));

__device__ __forceinline__ v4f min4(v4f a, v4f b) {
    v4f r; r.x = fminf(a.x,b.x); r.y = fminf(a.y,b.y); r.z = fminf(a.z,b.z); r.w = fminf(a.w,b.w); return r;
}
__device__ __forceinline__ v4f max4(v4f a, v4f b) {
    v4f r; r.x = fmaxf(a.x,b.x); r.y = fmaxf(a.y,b.y); r.z = fmaxf(a.z,b.z); r.w = fmaxf(a.w,b.w); return r;
}

// ---- Pass 1: per-column partial min/max. 2048 blocks = 4 col-groups x 512
// row-chunks (32 contiguous rows each) -> 8 blocks/CU = 32 waves/CU. ----
__global__ __launch_bounds__(256) void minmax_k(const float* __restrict__ x,
                                                float* __restrict__ pmin,
                                                float* __restrict__ pmax) {
    const int cgp  = blockIdx.x & 3;    // column group, 256 cols each
    const int ch   = blockIdx.x >> 2;   // row chunk (0..511), 32 rows each
    const int lane = threadIdx.x & 63;
    const int wid  = threadIdx.x >> 6;  // wave in block (0..3)
    const int col  = cgp * 256 + lane * 4;

    const float INF = __builtin_inff();
    v4f vmin; vmin.x = vmin.y = vmin.z = vmin.w = INF;
    v4f vmax; vmax.x = vmax.y = vmax.z = vmax.w = -INF;

    const int r0 = ch * (ROWS / NCHUNK);   // 32 rows per chunk
    const int b  = r0 >> 10;
    const int hh = r0 & (H - 1);
    const float* p0 = x + (size_t)b * BSTR + ((size_t)hh << 10) + col;

    if (r0 < H) {
        // batch 0: second difference frame2 - frame0 (branch uniform per block)
#pragma unroll
        for (int i = 0; i < 8; ++i) {
            int off = ((i << 2) + wid) << 10;
            v4f f0 = *(const v4f*)(p0 + off);
            v4f f2 = *(const v4f*)(p0 + off + 2 * FRAME);
            v4f v  = f2 - f0;
            vmin = min4(vmin, v);
            vmax = max4(vmax, v);
        }
    } else {
        // batches 1..15: frame 0 passthrough
#pragma unroll
        for (int i = 0; i < 8; ++i) {
            int off = ((i << 2) + wid) << 10;
            v4f v = *(const v4f*)(p0 + off);
            vmin = min4(vmin, v);
            vmax = max4(vmax, v);
        }
    }

    __shared__ v4f smin[4][64];
    __shared__ v4f smax[4][64];
    smin[wid][lane] = vmin;
    smax[wid][lane] = vmax;
    __syncthreads();

    if (threadIdx.x < 64) {
        v4f m = min4(min4(smin[0][lane], smin[1][lane]),
                     min4(smin[2][lane], smin[3][lane]));
        v4f M = max4(max4(smax[0][lane], smax[1][lane]),
                     max4(smax[2][lane], smax[3][lane]));
        *(v4f*)(pmin + ch * W + col) = m;
        *(v4f*)(pmax + ch * W + col) = M;
    }
}

// ---- Pass 2: reduce 512 partials/column -> mn, 1/denom. 32 blocks,
// 8 threads per column (32 cols/block), LDS tree. ----
__global__ __launch_bounds__(256) void finalize_k(const float* __restrict__ pmin,
                                                  const float* __restrict__ pmax,
                                                  float* __restrict__ mn_f,
                                                  float* __restrict__ inv_f) {
    const int c   = threadIdx.x & 31;         // col within block
    const int sub = threadIdx.x >> 5;         // 0..7 chunk slice
    const int col = blockIdx.x * 32 + c;

    float mn = __builtin_inff();
    float mx = -__builtin_inff();
#pragma unroll
    for (int k = 0; k < NCHUNK / 8; ++k) {
        int ch = sub * (NCHUNK / 8) + k;
        mn = fminf(mn, pmin[ch * W + col]);
        mx = fmaxf(mx, pmax[ch * W + col]);
    }

    __shared__ float smn[8][32];
    __shared__ float smx[8][32];
    smn[sub][c] = mn;
    smx[sub][c] = mx;
    __syncthreads();

    if (threadIdx.x < 32) {
        float m = smn[0][c], M = smx[0][c];
#pragma unroll
        for (int s = 1; s < 8; ++s) {
            m = fminf(m, smn[s][c]);
            M = fmaxf(M, smx[s][c]);
        }
        float rng = M - m;
        float den = (rng == 0.0f) ? 1.0f : rng;  // _handle_zeros_in_scale
        mn_f[col]  = m;
        inv_f[col] = 1.0f / den;
    }
}

// ---- Pass 3: scaled output. 8192 blocks x 256 thr x 2 vec4 (exact cover)
// -> 8 blocks/CU = 32 waves/CU. ----
__global__ __launch_bounds__(256) void scale_k(const float* __restrict__ x,
                                               const float* __restrict__ mn_f,
                                               const float* __restrict__ inv_f,
                                               float* __restrict__ out) {
#pragma unroll
    for (int k = 0; k < 2; ++k) {
        int i4  = blockIdx.x * 512 + k * 256 + threadIdx.x;
        int idx = i4 << 2;
        int r   = idx >> 10;
        int col = idx & (W - 1);
        int b   = r >> 10;
        int hh  = r & (H - 1);
        const float* p = x + (size_t)b * BSTR + ((size_t)hh << 10) + col;
        v4f v = *(const v4f*)p;
        if (r < H) {
            v4f f2 = *(const v4f*)(p + 2 * FRAME);
            v = f2 - v;
        }
        v4f mn4 = *(const v4f*)(mn_f + col);
        v4f iv4 = *(const v4f*)(inv_f + col);
        v4f o   = (v - mn4) * iv4;
        *(v4f*)(out + idx) = o;
    }
}

extern "C" void kernel_launch(void* const* d_in, const int* in_sizes, int n_in,
                              void* d_out, int out_size, void* d_ws, size_t ws_size,
                              hipStream_t stream) {
    const float* x = (const float*)d_in[0];
    float* out = (float*)d_out;

    // ws layout: pmin[512*1024] | pmax[512*1024] | mn_f[1024] | inv_f[1024]
    float* pmin = (float*)d_ws;
    float* pmax = pmin + NCHUNK * W;
    float* mn_f = pmax + NCHUNK * W;
    float* inv_f = mn_f + W;

    minmax_k<<<2048, 256, 0, stream>>>(x, pmin, pmax);
    finalize_k<<<32, 256, 0, stream>>>(pmin, pmax, mn_f, inv_f);
    scale_k<<<8192, 256, 0, stream>>>(x, mn_f, inv_f, out);
}